// Round 13
// baseline (182.374 us; speedup 1.0000x reference)
//
#include <hip/hip_runtime.h>

#define B_ 8
#define C_ 512
#define H_ 32
#define W_ 32
#define L_ 1024
#define M_ 8192   // B*L
#define NH_ 8
#define HD_ 64

typedef float f32x4 __attribute__((ext_vector_type(4)));
typedef short s16x8 __attribute__((ext_vector_type(8)));

// MFMA 16x16x32 bf16. C/D: col=lane&15 (n), row=(lane>>4)*4+reg (m).
// A frag: row m=lane&15, k=(lane>>4)*8+j ; B frag from B^T [n][k]: row n=lane&15.
__device__ __forceinline__ f32x4 mfma_bf16(f32x4 acc, s16x8 a, s16x8 b) {
    asm("v_mfma_f32_16x16x32_bf16 %0, %1, %2, %0" : "+v"(acc) : "v"(a), "v"(b));
    return acc;
}

__device__ __forceinline__ s16x8 ldg8(const unsigned short* p) {
    return *(const s16x8*)p;
}

typedef __attribute__((address_space(1))) const unsigned int glob_u32;
typedef __attribute__((address_space(3))) unsigned int lds_u32;
__device__ __forceinline__ void async_cp16(const void* g, void* l) {
    __builtin_amdgcn_global_load_lds((glob_u32*)g, (lds_u32*)l, 16, 0, 0);
}

// XOR-swizzle for 64-ushort (128B) LDS rows: chunk c of row r lives at slot
// c ^ (r&7). Kills the 16-way same-bank conflict of the linear layout
// (bank = (c^(r&7))*4 mod 32 -> 8 distinct chunks over 16 rows -> 2-way, free).
__device__ __forceinline__ int swz(int row, int koff_us) {
    return (((koff_us >> 3) ^ (row & 7)) << 3);
}

__device__ __forceinline__ unsigned short f2bf(float f) {
    unsigned int u = __float_as_uint(f);
    unsigned int r = (u + 0x7FFFu + ((u >> 16) & 1u)) >> 16;
    return (unsigned short)r;
}

__device__ __forceinline__ float bf2f(unsigned short u) {
    return __uint_as_float(((unsigned int)u) << 16);
}

__device__ __forceinline__ float gelu_exact(float v) {
    return 0.5f * v * (1.0f + erff(v * 0.70710678118654752f));
}

__device__ __forceinline__ float sigmoidf_(float v) {
    return 1.0f / (1.0f + __expf(-v));
}

// ---------------- K1: DualWalze + fused fp32->bf16 weight conversion ----------
__global__ __launch_bounds__(256) void k_walze_cvt(
        const float* __restrict__ x, const float* __restrict__ dww,
        const float* __restrict__ dwb, const float* __restrict__ shw,
        const float* __restrict__ shb, const float* __restrict__ mixw,
        const float* __restrict__ gamma, const float* __restrict__ beta,
        float* __restrict__ xw,
        const float* __restrict__ w1, const float* __restrict__ w2,
        const float* __restrict__ w3,
        unsigned short* __restrict__ o1, unsigned short* __restrict__ o2,
        unsigned short* __restrict__ o3) {
    __shared__ float tile[1024];
    int bc = blockIdx.x;           // b*C + c
    int c = bc & (C_ - 1);
    int tid = threadIdx.x;
    const float* xp = x + (size_t)bc * 1024;
#pragma unroll
    for (int t = 0; t < 4; ++t) tile[tid + 256 * t] = xp[tid + 256 * t];
    // weight conversion while the tile loads settle
    {
        int g = bc * 256 + tid;
#pragma unroll
        for (int t = 0; t < 2; ++t) {
            int i = g + t * 1048576;
            if (i < 131072) o1[i] = f2bf(w1[i]);
            else if (i < 917504) o2[i - 131072] = f2bf(w2[i - 131072]);
            else if (i < 1179648) o3[i - 917504] = f2bf(w3[i - 917504]);
        }
    }
    __syncthreads();
    float wm[9], wsh[9];
#pragma unroll
    for (int t = 0; t < 9; ++t) { wm[t] = dww[c * 9 + t]; wsh[t] = shw[t]; }
    float mix = sigmoidf_(mixw[0]);
    float bmain = dwb[c], bsh = shb[0];
    float g = gamma[c], bt = beta[c];
    const float rs = rsqrtf(1.0f + 1e-5f);
#pragma unroll
    for (int t = 0; t < 4; ++t) {
        int l = tid + 256 * t;
        int h = l >> 5, w = l & 31;
        float accm = 0.f, accs = 0.f;
#pragma unroll
        for (int kh = 0; kh < 3; ++kh) {
            int hh = (h + kh + 31) & 31;
#pragma unroll
            for (int kw = 0; kw < 3; ++kw) {
                int ww = (w + kw + 31) & 31;
                float v = tile[hh * 32 + ww];
                accm += v * wm[kh * 3 + kw];
                accs += v * wsh[kh * 3 + kw];
            }
        }
        float combined = mix * (accm + bmain) + (1.f - mix) * (accs + bsh) + tile[l];
        float bn = g * combined * rs + bt;
        xw[(size_t)bc * 1024 + l] = gelu_exact(bn);
    }
}

// ---------------- K2: LDS-tiled transpose+pack (known-good) -------------------
__global__ __launch_bounds__(256) void k_pack(
        const float* __restrict__ x, const float* __restrict__ xw,
        unsigned short* __restrict__ comb) {
    __shared__ float Tx[64 * 65];
    __shared__ float Tw[64 * 65];
    int b = blockIdx.z;
    int c0 = blockIdx.y * 64;
    int l0 = blockIdx.x * 64;
    int tid = threadIdx.x;
    for (int idx = tid; idx < 1024; idx += 256) {
        int cr = idx >> 4, f = idx & 15;
        size_t src = ((size_t)(b * C_ + c0 + cr) << 10) + l0 + f * 4;
        float4 vx = *(const float4*)(x + src);
        float4 vw = *(const float4*)(xw + src);
        *(float4*)&Tx[cr * 65 + f * 4] = vx;
        *(float4*)&Tw[cr * 65 + f * 4] = vw;
    }
    __syncthreads();
    for (int idx = tid; idx < 1024; idx += 256) {
        int lr = idx >> 4, f = idx & 15;
        ushort4 ux, uw;
        ux.x = f2bf(Tx[(4 * f + 0) * 65 + lr]);
        ux.y = f2bf(Tx[(4 * f + 1) * 65 + lr]);
        ux.z = f2bf(Tx[(4 * f + 2) * 65 + lr]);
        ux.w = f2bf(Tx[(4 * f + 3) * 65 + lr]);
        uw.x = f2bf(Tw[(4 * f + 0) * 65 + lr]);
        uw.y = f2bf(Tw[(4 * f + 1) * 65 + lr]);
        uw.z = f2bf(Tw[(4 * f + 2) * 65 + lr]);
        uw.w = f2bf(Tw[(4 * f + 3) * 65 + lr]);
        unsigned short* row = comb + (((size_t)(b << 10) + l0 + lr) << 10);
        *(ushort4*)(row + c0 + 4 * f) = ux;
        *(ushort4*)(row + 512 + c0 + 4 * f) = uw;
    }
}

// ---------------- K3+K4 fused: interleaved detector | qkv GEMM ----------------
// mod-5 block mapping (2 det : 3 qkv) so both types co-reside from dispatch #1;
// qkv LDS uses XOR-swizzled rows (conflict-free ds_read_b128).
__global__ __launch_bounds__(256) void k_det_qkv(
        const unsigned short* __restrict__ comb,
        const unsigned short* __restrict__ w1, const float* __restrict__ b1,
        const float* __restrict__ w2, const float* __restrict__ b2,
        float* __restrict__ sm,
        const unsigned short* __restrict__ Wt, const float* __restrict__ bias,
        unsigned short* __restrict__ out_hi, unsigned short* __restrict__ out_lo) {
    __shared__ unsigned short As[128 * 64];
    __shared__ unsigned short Bs[128 * 64];
    int tid = threadIdx.x;
    int wave = tid >> 6, lane = tid & 63;
    int col = lane & 15, quad = lane >> 4;
    int grp = blockIdx.x / 5, rem = blockIdx.x % 5;
    if (rem < 2) {
        // ---- detector body (known-good) ----
        float* red = (float*)As;              // 256 B of the union
        int m0 = (grp * 2 + rem) * 16;
        int koff = quad * 8;
        int nb0 = wave * 32, nb1 = nb0 + 16;
        const unsigned short* pa  = comb + (size_t)(m0 + col) * 1024 + koff;
        const unsigned short* pw0 = w1 + (size_t)(nb0 + col) * 1024 + koff;
        const unsigned short* pw1 = w1 + (size_t)(nb1 + col) * 1024 + koff;
        f32x4 acc0 = {0.f, 0.f, 0.f, 0.f}, acc1 = {0.f, 0.f, 0.f, 0.f};
        for (int k = 0; k < 1024; k += 32) {
            s16x8 a = ldg8(pa + k);
            acc0 = mfma_bf16(acc0, a, ldg8(pw0 + k));
            acc1 = mfma_bf16(acc1, a, ldg8(pw1 + k));
        }
        asm volatile("s_nop 7\ns_nop 7");
        float bia0 = b1[nb0 + col], bia1 = b1[nb1 + col];
        float wv0 = w2[nb0 + col], wv1 = w2[nb1 + col];
#pragma unroll
        for (int r = 0; r < 4; ++r) {
            float h0 = gelu_exact(acc0[r] + bia0);
            float h1 = gelu_exact(acc1[r] + bia1);
            float p = h0 * wv0 + h1 * wv1;
            p += __shfl_xor(p, 1);
            p += __shfl_xor(p, 2);
            p += __shfl_xor(p, 4);
            p += __shfl_xor(p, 8);
            if (col == 0) red[wave * 16 + quad * 4 + r] = p;
        }
        __syncthreads();
        if (tid < 16) {
            float s = red[tid] + red[16 + tid] + red[32 + tid] + red[48 + tid] + b2[0];
            sm[m0 + tid] = sigmoidf_(s);
        }
    } else {
        // ---- qkv GEMM body, swizzled LDS ----
        int qbid = grp * 3 + (rem - 2);       // 0..767
        int nb = (qbid % 12) * 128;
        int mb = (qbid / 12) * 128;
        const unsigned short* A = comb + 512; // xw half, lda=1024
        int wr = wave & 1, wc = wave >> 1;
        int srow = tid >> 3, sko = tid & 7;
        bool write_lo = (nb >= 1024);         // V region only
        f32x4 acc[4][4] = {};
        for (int kb = 0; kb < 512; kb += 64) {
#pragma unroll
            for (int p = 0; p < 4; ++p) {
                int r = p * 32 + srow;
                int cs = sko ^ (r & 7);       // swizzled source chunk
                async_cp16(A + (size_t)(mb + r) * 1024 + kb + cs * 8, &As[r * 64 + sko * 8]);
                async_cp16(Wt + (size_t)(nb + r) * 512 + kb + cs * 8, &Bs[r * 64 + sko * 8]);
            }
            __syncthreads();
#pragma unroll
            for (int ks = 0; ks < 64; ks += 32) {
                s16x8 a[4], b[4];
#pragma unroll
                for (int i = 0; i < 4; ++i) {
                    int rr = wr * 64 + i * 16 + col;
                    a[i] = *(const s16x8*)&As[rr * 64 + swz(rr, ks + quad * 8)];
                }
#pragma unroll
                for (int j = 0; j < 4; ++j) {
                    int rr = wc * 64 + j * 16 + col;
                    b[j] = *(const s16x8*)&Bs[rr * 64 + swz(rr, ks + quad * 8)];
                }
#pragma unroll
                for (int i = 0; i < 4; ++i)
#pragma unroll
                    for (int j = 0; j < 4; ++j)
                        acc[i][j] = mfma_bf16(acc[i][j], a[i], b[j]);
            }
            __syncthreads();
        }
        asm volatile("s_nop 7\ns_nop 7");
#pragma unroll
        for (int i = 0; i < 4; ++i)
#pragma unroll
            for (int j = 0; j < 4; ++j) {
                int n = nb + wc * 64 + j * 16 + col;
                float bv = bias[n];
#pragma unroll
                for (int r = 0; r < 4; ++r) {
                    int m = mb + wr * 64 + i * 16 + quad * 4 + r;
                    float v = acc[i][j][r] + bv;
                    unsigned short hi = f2bf(v);
                    size_t idx = (size_t)m * 1536 + n;
                    out_hi[idx] = hi;
                    if (write_lo) out_lo[idx] = f2bf(v - bf2f(hi));
                }
            }
    }
}

// ---------------- K5: windowed attention via MFMA (round-11 known-good) -------
__global__ __launch_bounds__(256) void k_attn(
        const unsigned short* __restrict__ qkv_hi,
        const unsigned short* __restrict__ qkv_lo,
        unsigned short* __restrict__ ctx) {
    __shared__ unsigned short Vth[64 * 112];      // V hi [d][key], ld=112 (96 real + 16 zero pad)
    __shared__ unsigned short Vtl[64 * 112];      // V lo
    __shared__ unsigned short Ph[4][16 * 72];     // per-wave P hi [m][window-key], ld=72
    __shared__ unsigned short Pl[4][16 * 72];     // per-wave P lo
    int b = blockIdx.z, h = blockIdx.y;
    int q0 = blockIdx.x * 64;
    int tid = threadIdx.x, wave = tid >> 6, lane = tid & 63;
    int col = lane & 15, quad = lane >> 4;
    int jlo_t = max(q0 - 16, 0);
    const unsigned short* baseh = qkv_hi + ((size_t)(b << 10)) * 1536;
    const unsigned short* basel = qkv_lo + ((size_t)(b << 10)) * 1536;
#pragma unroll
    for (int it = 0; it < 3; ++it) {
        int slot = it * 256 + tid;
        int kg = slot >> 6, d = slot & 63;
        int key0 = jlo_t + kg * 8;
        unsigned short eh[8], el[8];
#pragma unroll
        for (int t = 0; t < 8; ++t) {
            size_t ro = (size_t)min(key0 + t, 1023) * 1536 + 1024 + h * 64 + d;
            eh[t] = baseh[ro];
            el[t] = basel[ro];
        }
        ushort4 h0 = {eh[0], eh[1], eh[2], eh[3]}, h1 = {eh[4], eh[5], eh[6], eh[7]};
        ushort4 l0 = {el[0], el[1], el[2], el[3]}, l1 = {el[4], el[5], el[6], el[7]};
        *(ushort4*)&Vth[d * 112 + kg * 8] = h0;
        *(ushort4*)&Vth[d * 112 + kg * 8 + 4] = h1;
        *(ushort4*)&Vtl[d * 112 + kg * 8] = l0;
        *(ushort4*)&Vtl[d * 112 + kg * 8 + 4] = l1;
    }
    // zero V pad keys [96,112)
    {
        int d = tid >> 2, c4 = (tid & 3) * 4;
        ushort4 z = {0, 0, 0, 0};
        *(ushort4*)&Vth[d * 112 + 96 + c4] = z;
        *(ushort4*)&Vtl[d * 112 + 96 + c4] = z;
    }
    __syncthreads();
    // Q A-frags (hi only)
    int i_min = q0 + wave * 16;
    size_t qoff = (size_t)(i_min + col) * 1536 + h * 64;
    s16x8 aq0h = ldg8(baseh + qoff + quad * 8);
    s16x8 aq1h = ldg8(baseh + qoff + 32 + quad * 8);
    // live key-tile range for this wave (wave-uniform, <=3 tiles)
    int t0 = (max(i_min - 16, 0) - jlo_t) >> 4;
    int t1 = (min(i_min + 31, 1023) - jlo_t) >> 4;
    f32x4 S[3];
#pragma unroll
    for (int u = 0; u < 3; ++u) {
        int nt = t0 + u;
        size_t koffb = (size_t)min(jlo_t + nt * 16 + col, 1023) * 1536 + 512 + h * 64;
        s16x8 kh0 = ldg8(baseh + koffb + quad * 8);
        s16x8 kh1 = ldg8(baseh + koffb + 32 + quad * 8);
        f32x4 z = {0.f, 0.f, 0.f, 0.f};
        z = mfma_bf16(z, aq0h, kh0);
        z = mfma_bf16(z, aq1h, kh1);
        S[u] = z;
    }
    asm volatile("s_nop 7\ns_nop 7");
    int i_base = i_min + quad * 4;
    float mx[4] = {-1e30f, -1e30f, -1e30f, -1e30f};
#pragma unroll
    for (int u = 0; u < 3; ++u) {
        int nt = t0 + u;
        int j = jlo_t + nt * 16 + col;
        bool live = (nt <= t1);
#pragma unroll
        for (int r = 0; r < 4; ++r) {
            int i = i_base + r;
            bool ok = live && (j <= 1023) && (j >= i - 16) && (j <= i + 16);
            float s = ok ? S[u][r] * 0.125f : -1e30f;
            S[u][r] = s;
            mx[r] = fmaxf(mx[r], s);
        }
    }
#pragma unroll
    for (int r = 0; r < 4; ++r) {
        mx[r] = fmaxf(mx[r], __shfl_xor(mx[r], 1));
        mx[r] = fmaxf(mx[r], __shfl_xor(mx[r], 2));
        mx[r] = fmaxf(mx[r], __shfl_xor(mx[r], 4));
        mx[r] = fmaxf(mx[r], __shfl_xor(mx[r], 8));
    }
    float sum[4] = {0.f, 0.f, 0.f, 0.f};
#pragma unroll
    for (int u = 0; u < 3; ++u)
#pragma unroll
        for (int r = 0; r < 4; ++r) {
            float p = __expf(S[u][r] - mx[r]);
            S[u][r] = p;
            sum[r] += p;
        }
#pragma unroll
    for (int r = 0; r < 4; ++r) {
        sum[r] += __shfl_xor(sum[r], 1);
        sum[r] += __shfl_xor(sum[r], 2);
        sum[r] += __shfl_xor(sum[r], 4);
        sum[r] += __shfl_xor(sum[r], 8);
        sum[r] = 1.f / sum[r];
    }
    int wbase = t0 * 16;
    // zero P pad cols [48,64)
    {
        int pr = lane >> 2, c4 = (lane & 3) * 4;
        ushort4 z = {0, 0, 0, 0};
        *(ushort4*)&Ph[wave][pr * 72 + 48 + c4] = z;
        *(ushort4*)&Pl[wave][pr * 72 + 48 + c4] = z;
    }
#pragma unroll
    for (int u = 0; u < 3; ++u) {
        int pcol = u * 16 + col;
#pragma unroll
        for (int r = 0; r < 4; ++r) {
            float pv = S[u][r] * sum[r];
            unsigned short hi = f2bf(pv);
            Ph[wave][(quad * 4 + r) * 72 + pcol] = hi;
            Pl[wave][(quad * 4 + r) * 72 + pcol] = f2bf(pv - bf2f(hi));
        }
    }
    __syncthreads();
    f32x4 O[4] = {};
#pragma unroll
    for (int ks = 0; ks < 64; ks += 32) {
        s16x8 aph = *(const s16x8*)&Ph[wave][col * 72 + ks + quad * 8];
        s16x8 apl = *(const s16x8*)&Pl[wave][col * 72 + ks + quad * 8];
#pragma unroll
        for (int nt = 0; nt < 4; ++nt) {
            s16x8 bvh = *(const s16x8*)&Vth[(nt * 16 + col) * 112 + wbase + ks + quad * 8];
            s16x8 bvl = *(const s16x8*)&Vtl[(nt * 16 + col) * 112 + wbase + ks + quad * 8];
            O[nt] = mfma_bf16(O[nt], aph, bvh);
            O[nt] = mfma_bf16(O[nt], apl, bvh);
            O[nt] = mfma_bf16(O[nt], aph, bvl);
        }
    }
    asm volatile("s_nop 7\ns_nop 7");
#pragma unroll
    for (int nt = 0; nt < 4; ++nt)
#pragma unroll
        for (int r = 0; r < 4; ++r) {
            int i = i_base + r;
            ctx[((size_t)(b << 10) + i) * 512 + h * 64 + nt * 16 + col] = f2bf(O[nt][r]);
        }
}

// ---------------- K6: out-proj GEMM + gated combine, 64x64, swizzled LDS ------
__global__ __launch_bounds__(256) void k_out_combine(
        const unsigned short* __restrict__ Wt, const unsigned short* __restrict__ Actx,
        const float* __restrict__ bias, const float* __restrict__ xw,
        const float* __restrict__ sm, float* __restrict__ out) {
    __shared__ unsigned short As[64 * 64];
    __shared__ unsigned short Bs[64 * 64];
    int tid = threadIdx.x;
    int wave = tid >> 6, lane = tid & 63;
    int col = lane & 15, quad = lane >> 4;
    int wr = wave & 1, wc = wave >> 1;
    int mb = blockIdx.y * 64, nb = blockIdx.x * 64;
    int srow = tid >> 3, sko = tid & 7;
    f32x4 acc[2][2] = {};
    for (int kb = 0; kb < 512; kb += 64) {
#pragma unroll
        for (int p = 0; p < 2; ++p) {
            int r = p * 32 + srow;
            int cs = sko ^ (r & 7);           // swizzled source chunk
            async_cp16(Wt + (size_t)(mb + r) * 512 + kb + cs * 8, &As[r * 64 + sko * 8]);
            async_cp16(Actx + (size_t)(nb + r) * 512 + kb + cs * 8, &Bs[r * 64 + sko * 8]);
        }
        __syncthreads();
#pragma unroll
        for (int ks = 0; ks < 64; ks += 32) {
            s16x8 a[2], b[2];
#pragma unroll
            for (int i = 0; i < 2; ++i) {
                int rr = wr * 32 + i * 16 + col;
                a[i] = *(const s16x8*)&As[rr * 64 + swz(rr, ks + quad * 8)];
            }
#pragma unroll
            for (int j = 0; j < 2; ++j) {
                int rr = wc * 32 + j * 16 + col;
                b[j] = *(const s16x8*)&Bs[rr * 64 + swz(rr, ks + quad * 8)];
            }
#pragma unroll
            for (int i = 0; i < 2; ++i)
#pragma unroll
                for (int j = 0; j < 2; ++j)
                    acc[i][j] = mfma_bf16(acc[i][j], a[i], b[j]);
        }
        __syncthreads();
    }
    asm volatile("s_nop 7\ns_nop 7");
#pragma unroll
    for (int i = 0; i < 2; ++i)
#pragma unroll
        for (int j = 0; j < 2; ++j) {
            int seq = nb + wc * 32 + j * 16 + col;
            int bb = seq >> 10, l = seq & 1023;
            float smv = sm[seq];
#pragma unroll
            for (int r = 0; r < 4; ++r) {
                int c = mb + wr * 32 + i * 16 + quad * 4 + r;
                float v = acc[i][j][r] + bias[c];
                size_t oidx = ((size_t)(bb * C_ + c) << 10) + l;
                out[oidx] = xw[oidx] + smv * v;
            }
        }
}

extern "C" void kernel_launch(void* const* d_in, const int* in_sizes, int n_in,
                              void* d_out, int out_size, void* d_ws, size_t ws_size,
                              hipStream_t stream) {
    const float* x      = (const float*)d_in[0];
    const float* dw_w   = (const float*)d_in[1];
    const float* dw_b   = (const float*)d_in[2];
    const float* sh_w   = (const float*)d_in[3];
    const float* sh_b   = (const float*)d_in[4];
    const float* mix_w  = (const float*)d_in[5];
    const float* bn_g   = (const float*)d_in[6];
    const float* bn_b   = (const float*)d_in[7];
    const float* det_w1 = (const float*)d_in[8];
    const float* det_b1 = (const float*)d_in[9];
    const float* det_w2 = (const float*)d_in[10];
    const float* det_b2 = (const float*)d_in[11];
    const float* inp_w  = (const float*)d_in[12];
    const float* inp_b  = (const float*)d_in[13];
    const float* outp_w = (const float*)d_in[14];
    const float* outp_b = (const float*)d_in[15];
    float* out = (float*)d_out;

    char* ws = (char*)d_ws;
    size_t off = 0;
    auto alloc = [&](size_t bytes) -> void* {
        void* p = ws + off;
        off += (bytes + 255) & ~(size_t)255;
        return p;
    };
    float* xw             = (float*)alloc((size_t)M_ * C_ * 4);
    unsigned short* comb  = (unsigned short*)alloc((size_t)M_ * 1024 * 2);
    unsigned short* qkvh  = (unsigned short*)alloc((size_t)M_ * 1536 * 2);
    unsigned short* qkvl  = (unsigned short*)alloc((size_t)M_ * 1536 * 2);
    unsigned short* ctx   = (unsigned short*)alloc((size_t)M_ * 512 * 2);
    float* smask          = (float*)alloc((size_t)M_ * 4);
    unsigned short* w1b   = (unsigned short*)alloc(131072 * 2);
    unsigned short* inwb  = (unsigned short*)alloc(786432 * 2);
    unsigned short* outwb = (unsigned short*)alloc(262144 * 2);
    (void)ws_size; (void)in_sizes; (void)n_in; (void)out_size;

    k_walze_cvt<<<B_ * C_, 256, 0, stream>>>(x, dw_w, dw_b, sh_w, sh_b, mix_w,
                                             bn_g, bn_b, xw,
                                             det_w1, inp_w, outp_w, w1b, inwb, outwb);
    k_pack<<<dim3(16, 8, 8), 256, 0, stream>>>(x, xw, comb);
    k_det_qkv<<<512 + 768, 256, 0, stream>>>(comb, w1b, det_b1, det_w2, det_b2, smask,
                                             inwb, inp_b, qkvh, qkvl);
    k_attn<<<dim3(16, NH_, B_), 256, 0, stream>>>(qkvh, qkvl, ctx);
    k_out_combine<<<dim3(M_ / 64, C_ / 64), 256, 0, stream>>>(outwb, ctx, outp_b,
                                                              xw, smask, out);
}